// Round 5
// baseline (363.075 us; speedup 1.0000x reference)
//
#include <hip/hip_runtime.h>
#include <hip/hip_bf16.h>

#define B_  4
#define S_  2048
#define D_  1024
#define E_  8
#define K2_ 2048   // 2*D

#define CHUNKS 64
#define CLEN   32  // CHUNKS*CLEN == S_

typedef __attribute__((ext_vector_type(8))) short short8;   // 8 bf16 (4 VGPRs)
typedef __attribute__((ext_vector_type(4))) float floatx4;  // 4 fp32 acc

__device__ __forceinline__ void gld16(const void* g, const void* l) {
    __builtin_amdgcn_global_load_lds(
        (const __attribute__((address_space(1))) unsigned int*)g,
        (__attribute__((address_space(3))) unsigned int*)l, 16, 0, 0);
}

// ---------------- 1. RMSNorm (f32 in -> bf16 out) ----------------
__global__ void rmsnorm_k(const float* __restrict__ in, const float* __restrict__ nw,
                          __hip_bfloat16* __restrict__ x) {
    int b = blockIdx.y, s = blockIdx.x, t = threadIdx.x;
    const float* row = in + ((size_t)b * S_ + s) * D_;
    float v[4]; float ss = 0.0f;
#pragma unroll
    for (int i = 0; i < 4; i++) { v[i] = row[t + 256 * i]; ss += v[i] * v[i]; }
#pragma unroll
    for (int o = 32; o > 0; o >>= 1) ss += __shfl_down(ss, o, 64);
    __shared__ float ls[4];
    if ((t & 63) == 0) ls[t >> 6] = ss;
    __syncthreads();
    float tot = ls[0] + ls[1] + ls[2] + ls[3];
    float rs = rsqrtf(tot * (1.0f / (float)D_) + 1e-6f);
    __hip_bfloat16* xr = x + ((size_t)b * S_ + s) * D_;
#pragma unroll
    for (int i = 0; i < 4; i++)
        xr[t + 256 * i] = __float2bfloat16(v[i] * rs * nw[t + 256 * i]);
}

// ---------------- 2a. column sums of x over S (router mean) ----------------
__global__ void xsum_k(const __hip_bfloat16* __restrict__ x, float* __restrict__ xs) {
    int d = blockIdx.x * 256 + threadIdx.x;
    int b = blockIdx.y;
    int s0 = blockIdx.z * 128;
    const __hip_bfloat16* p = x + ((size_t)b * S_ + s0) * D_ + d;
    float acc = 0.0f;
#pragma unroll 4
    for (int s = 0; s < 128; s++) { acc += __bfloat162float(*p); p += D_; }
    atomicAdd(&xs[b * D_ + d], acc);
}

// ---------------- 2b. router logits + softmax (+ aux_loss=0) ----------------
__global__ void router_k(const float* __restrict__ xs, const float* __restrict__ rw,
                         const float* __restrict__ rb, float* __restrict__ probs,
                         float* __restrict__ aux) {
    int t = threadIdx.x;
    if (t == 255) *aux = 0.0f;
    int pair = t >> 3, sub = t & 7;
    int b = pair >> 3, e = pair & 7;
    float acc = 0.0f;
    for (int d = sub; d < D_; d += 8) acc += xs[b * D_ + d] * rw[e * D_ + d];
#pragma unroll
    for (int o = 4; o > 0; o >>= 1) acc += __shfl_down(acc, o, 8);
    __shared__ float lg[32];
    if (sub == 0) lg[pair] = acc * (1.0f / (float)S_) + rb[e];
    __syncthreads();
    if (t < 4) {
        float m = -1e30f;
        for (int e2 = 0; e2 < 8; e2++) m = fmaxf(m, lg[t * 8 + e2]);
        float ssum = 0.0f; float ex[8];
        for (int e2 = 0; e2 < 8; e2++) { ex[e2] = expf(lg[t * 8 + e2] - m); ssum += ex[e2]; }
        for (int e2 = 0; e2 < 8; e2++) probs[t * 8 + e2] = ex[e2] / ssum;
    }
}

// ---------------- 3. mix expert weights (f32 experts -> bf16 mixed) ----------------
__global__ void mix_k(const float* __restrict__ probs, const float* __restrict__ whg_e,
                      const float* __restrict__ wout_e, __hip_bfloat16* __restrict__ Whg,
                      __hip_bfloat16* __restrict__ Wout) {
    __shared__ float P[32];
    int t = threadIdx.x;
    if (t < 32) P[t] = probs[t];
    __syncthreads();
    size_t i = (size_t)blockIdx.x * 256 + t;
    const size_t T1 = (size_t)K2_ * D_;
    const size_t T2 = (size_t)D_ * D_;
    if (i < T1) {
        float a0 = 0, a1 = 0, a2 = 0, a3 = 0;
#pragma unroll
        for (int e = 0; e < 8; e++) {
            float w = whg_e[(size_t)e * T1 + i];
            a0 += P[0 * 8 + e] * w; a1 += P[1 * 8 + e] * w;
            a2 += P[2 * 8 + e] * w; a3 += P[3 * 8 + e] * w;
        }
        Whg[0 * T1 + i] = __float2bfloat16(a0); Whg[1 * T1 + i] = __float2bfloat16(a1);
        Whg[2 * T1 + i] = __float2bfloat16(a2); Whg[3 * T1 + i] = __float2bfloat16(a3);
    } else {
        size_t j = i - T1;
        float a0 = 0, a1 = 0, a2 = 0, a3 = 0;
#pragma unroll
        for (int e = 0; e < 8; e++) {
            float w = wout_e[(size_t)e * T2 + j];
            a0 += P[0 * 8 + e] * w; a1 += P[1 * 8 + e] * w;
            a2 += P[2 * 8 + e] * w; a3 += P[3 * 8 + e] * w;
        }
        Wout[0 * T2 + j] = __float2bfloat16(a0); Wout[1 * T2 + j] = __float2bfloat16(a1);
        Wout[2 * T2 + j] = __float2bfloat16(a2); Wout[3 * T2 + j] = __float2bfloat16(a3);
    }
}

// ---------------- 4. fused GEMM1 + (c,v) epilogue, 128x(128 dual) tile -------
// XOR-swizzled LDS: position (r, p) holds global 16B-chunk p ^ (r&7).
// Each wave: 64 m-rows x 64 n-cols, accumulating hidden AND gate concurrently.
__global__ __launch_bounds__(256) void gemm_hg_cv(
    const __hip_bfloat16* __restrict__ A, const __hip_bfloat16* __restrict__ Bm,
    float* __restrict__ cv) {
    const int K = D_;
    int bz = blockIdx.z;
    A  += (size_t)bz * S_ * D_;
    Bm += (size_t)bz * K2_ * D_;
    float2* CV = (float2*)cv + (size_t)bz * S_ * D_;
    int m0 = blockIdx.y * 128, n0 = blockIdx.x * 128;
    __shared__ __hip_bfloat16 lA[128][64];
    __shared__ __hip_bfloat16 lBh[128][64];
    __shared__ __hip_bfloat16 lBg[128][64];
    int t = threadIdx.x;
    int w = t >> 6, lane = t & 63;
    int lm = lane & 15, quad = lane >> 4;
    int wr = w >> 1, wc = w & 1;             // wave: 64 m x 64 n (dual h/g)
    floatx4 acch[4][4] = {};
    floatx4 accg[4][4] = {};
    int srow = lane >> 3;                    // 0..7
    int swzb = ((lane & 7) ^ srow) * 16;     // swizzled source byte-chunk
    const __hip_bfloat16* Bh = Bm;                    // hidden rows 0..1023
    const __hip_bfloat16* Bg = Bm + (size_t)D_ * K;   // gate rows 1024..2047

    for (int k0 = 0; k0 < K; k0 += 64) {
#pragma unroll
        for (int it = 0; it < 4; it++) {
            int r0 = (w * 4 + it) * 8;
            gld16((const char*)(A  + (size_t)(m0 + r0 + srow) * K + k0) + swzb,
                  &lA[r0][0]);
            gld16((const char*)(Bh + (size_t)(n0 + r0 + srow) * K + k0) + swzb,
                  &lBh[r0][0]);
            gld16((const char*)(Bg + (size_t)(n0 + r0 + srow) * K + k0) + swzb,
                  &lBg[r0][0]);
        }
        __syncthreads();
#pragma unroll
        for (int kk = 0; kk < 64; kk += 32) {
            short8 af[4], bh[4], bg[4];
            int p = (((kk >> 3) + quad) ^ (lm & 7)) * 8;
#pragma unroll
            for (int i = 0; i < 4; i++)
                af[i] = *(const short8*)(&lA[wr * 64 + i * 16 + lm][p]);
#pragma unroll
            for (int j = 0; j < 4; j++) {
                bh[j] = *(const short8*)(&lBh[wc * 64 + j * 16 + lm][p]);
                bg[j] = *(const short8*)(&lBg[wc * 64 + j * 16 + lm][p]);
            }
#pragma unroll
            for (int i = 0; i < 4; i++)
#pragma unroll
                for (int j = 0; j < 4; j++) {
                    acch[i][j] = __builtin_amdgcn_mfma_f32_16x16x32_bf16(
                        af[i], bh[j], acch[i][j], 0, 0, 0);
                    accg[i][j] = __builtin_amdgcn_mfma_f32_16x16x32_bf16(
                        af[i], bg[j], accg[i][j], 0, 0, 0);
                }
        }
        __syncthreads();
    }
#pragma unroll
    for (int i = 0; i < 4; i++) {
#pragma unroll
        for (int j = 0; j < 4; j++) {
#pragma unroll
            for (int r = 0; r < 4; r++) {
                int m = m0 + wr * 64 + i * 16 + quad * 4 + r;
                int n = n0 + wc * 64 + j * 16 + lm;
                float hid = acch[i][j][r];
                float g   = accg[i][j][r];
                float c  = 1.0f / (1.0f + expf(g));    // sigmoid(-g)
                float sg = 1.0f / (1.0f + expf(-g));   // sigmoid(g)
                float gfn = (hid >= 0.0f) ? (hid + 0.5f)
                                          : (1.0f / (1.0f + expf(-hid)));
                CV[(size_t)m * D_ + n] = make_float2(c, sg * gfn);
            }
        }
    }
}

// ---------------- 6. bf16 MFMA GEMM, C = A * B^T (+R), XOR-swizzled LDS ----
#define TM 128
#define TN 128
#define TBK 64
__global__ __launch_bounds__(256) void gemm_bf16_bt(
    const __hip_bfloat16* __restrict__ A, const __hip_bfloat16* __restrict__ Bm,
    float* __restrict__ C, const float* __restrict__ R,
    int M, int N, int K, size_t sa, size_t sb, size_t sc, size_t sr) {
    int bz = blockIdx.z;
    A += (size_t)bz * sa; Bm += (size_t)bz * sb; C += (size_t)bz * sc;
    if (R) R += (size_t)bz * sr;
    int m0 = blockIdx.y * TM, n0 = blockIdx.x * TN;
    __shared__ __hip_bfloat16 lA[TM][TBK];
    __shared__ __hip_bfloat16 lB[TN][TBK];
    int t = threadIdx.x;
    int w = t >> 6, lane = t & 63;
    int lm = lane & 15, quad = lane >> 4;
    int wr = w >> 1, wc = w & 1;
    floatx4 acc[4][4] = {};
    int srow = lane >> 3;
    int swzb = ((lane & 7) ^ srow) * 16;

    for (int k0 = 0; k0 < K; k0 += TBK) {
#pragma unroll
        for (int it = 0; it < 4; it++) {
            int r0 = (w * 4 + it) * 8;
            gld16((const char*)(A + (size_t)(m0 + r0 + srow) * K + k0) + swzb,
                  &lA[r0][0]);
            gld16((const char*)(Bm + (size_t)(n0 + r0 + srow) * K + k0) + swzb,
                  &lB[r0][0]);
        }
        __syncthreads();
#pragma unroll
        for (int kk = 0; kk < TBK; kk += 32) {
            short8 af[4], bf[4];
            int p = (((kk >> 3) + quad) ^ (lm & 7)) * 8;
#pragma unroll
            for (int i = 0; i < 4; i++)
                af[i] = *(const short8*)(&lA[wr * 64 + i * 16 + lm][p]);
#pragma unroll
            for (int j = 0; j < 4; j++)
                bf[j] = *(const short8*)(&lB[wc * 64 + j * 16 + lm][p]);
#pragma unroll
            for (int i = 0; i < 4; i++)
#pragma unroll
                for (int j = 0; j < 4; j++)
                    acc[i][j] = __builtin_amdgcn_mfma_f32_16x16x32_bf16(
                        af[i], bf[j], acc[i][j], 0, 0, 0);
        }
        __syncthreads();
    }
#pragma unroll
    for (int i = 0; i < 4; i++) {
#pragma unroll
        for (int j = 0; j < 4; j++) {
#pragma unroll
            for (int r = 0; r < 4; r++) {
                int m = m0 + wr * 64 + i * 16 + quad * 4 + r;
                int n = n0 + wc * 64 + j * 16 + lm;
                float v = acc[i][j][r];
                if (R) v += R[(size_t)m * N + n];
                C[(size_t)m * N + n] = v;
            }
        }
    }
}

// ---------------- 5. chunked LINEAR scan over cv (d-pairs via float4) -------
// phase A: per-chunk composition
__global__ void scanA_k(const float* __restrict__ cv, float* __restrict__ Cc,
                        float* __restrict__ Vc) {
    int b = blockIdx.z, c = blockIdx.y;
    int d2 = blockIdx.x * 256 + threadIdx.x;   // d-pair index 0..511
    const float4* p = (const float4*)cv + (size_t)(b * S_ + c * CLEN) * (D_ / 2) + d2;
    float P0 = 1.0f, V0 = 0.0f, P1 = 1.0f, V1 = 0.0f;
#pragma unroll 4
    for (int s = 0; s < CLEN; s++) {
        float4 e = p[(size_t)s * (D_ / 2)];
        P0 *= e.x; V0 = e.x * V0 + e.y;
        P1 *= e.z; V1 = e.z * V1 + e.w;
    }
    size_t idx = ((size_t)(b * CHUNKS + c)) * D_ + 2 * d2;
    Cc[idx] = P0; Vc[idx] = V0; Cc[idx + 1] = P1; Vc[idx + 1] = V1;
}

// phase C (with inline phase-B lookback): compute chunk-initial h by scanning
// Cc/Vc for chunks 0..c-1 (tiny L2-hot arrays), then replay the chunk.
__global__ void scanC_k(const float* __restrict__ cv, const float* __restrict__ Cc,
                        const float* __restrict__ Vc,
                        __hip_bfloat162* __restrict__ hout, float* __restrict__ ns) {
    int b = blockIdx.z, c = blockIdx.y;
    int d2 = blockIdx.x * 256 + threadIdx.x;
    float h0 = 0.0f, h1 = 0.0f;
    const float2* Cc2 = (const float2*)Cc;
    const float2* Vc2 = (const float2*)Vc;
#pragma unroll 4
    for (int cc = 0; cc < c; cc++) {
        size_t idx2 = ((size_t)(b * CHUNKS + cc)) * (D_ / 2) + d2;
        float2 C2 = Cc2[idx2];
        float2 V2 = Vc2[idx2];
        h0 = C2.x * h0 + V2.x;
        h1 = C2.y * h1 + V2.y;
    }
    const float4* p = (const float4*)cv + (size_t)(b * S_ + c * CLEN) * (D_ / 2) + d2;
#pragma unroll 4
    for (int s = 0; s < CLEN; s++) {
        float4 e = p[(size_t)s * (D_ / 2)];
        h0 = e.x * h0 + e.y;
        h1 = e.z * h1 + e.w;
        __hip_bfloat162 hh;
        hh.x = __float2bfloat16(h0); hh.y = __float2bfloat16(h1);
        hout[(size_t)(b * S_ + c * CLEN + s) * (D_ / 2) + d2] = hh;
    }
    if (c == CHUNKS - 1) { ns[b * D_ + 2 * d2] = h0; ns[b * D_ + 2 * d2 + 1] = h1; }
}

// ---------------- launcher ----------------
extern "C" void kernel_launch(void* const* d_in, const int* in_sizes, int n_in,
                              void* d_out_v, int out_size, void* d_ws, size_t ws_size,
                              hipStream_t stream) {
    const float* inputs = (const float*)d_in[0];
    const float* nw     = (const float*)d_in[1];
    const float* rw     = (const float*)d_in[2];
    const float* rb     = (const float*)d_in[3];
    const float* whg_e  = (const float*)d_in[4];
    const float* wout_e = (const float*)d_in[5];
    float* out = (float*)d_out_v;

    float* ws = (float*)d_ws;
    float*          cv      = ws;                               // 16777216 f32 (float2 pairs)
    __hip_bfloat16* x_bf    = (__hip_bfloat16*)(ws + 16777216); // 8388608 bf16
    __hip_bfloat16* h_bf    = (__hip_bfloat16*)(ws + 20971520); // 8388608 bf16
    __hip_bfloat16* Whg_bf  = (__hip_bfloat16*)(ws + 25165824); // 8388608 bf16
    __hip_bfloat16* Wout_bf = (__hip_bfloat16*)(ws + 29360128); // 4194304 bf16
    float* xsum  = ws + 31457280;  // 4096
    float* probs = ws + 31461376;  // 32
    float* Cc    = ws + 31461408;  // 262144
    float* Vc    = ws + 31723552;  // 262144

    hipMemsetAsync(xsum, 0, (size_t)B_ * D_ * sizeof(float), stream);

    rmsnorm_k<<<dim3(S_, B_), 256, 0, stream>>>(inputs, nw, x_bf);
    xsum_k<<<dim3(D_ / 256, B_, 16), 256, 0, stream>>>(x_bf, xsum);
    router_k<<<1, 256, 0, stream>>>(xsum, rw, rb, probs,
                                    out + (size_t)B_ * S_ * D_ + (size_t)B_ * D_);
    mix_k<<<12288, 256, 0, stream>>>(probs, whg_e, wout_e, Whg_bf, Wout_bf);

    // fused GEMM1 + (c,v): 128x(128 dual) tile
    gemm_hg_cv<<<dim3(D_ / 128, S_ / 128, B_), 256, 0, stream>>>(x_bf, Whg_bf, cv);

    scanA_k<<<dim3(D_ / 512, CHUNKS, B_), 256, 0, stream>>>(cv, Cc, Vc);
    scanC_k<<<dim3(D_ / 512, CHUNKS, B_), 256, 0, stream>>>(
        cv, Cc, Vc, (__hip_bfloat162*)h_bf, out + (size_t)B_ * S_ * D_);

    // out[b] = h[b] (2048x1024) * Wout[b]^T + inputs[b]
    gemm_bf16_bt<<<dim3(D_ / TN, S_ / TM, B_), 256, 0, stream>>>(
        h_bf, Wout_bf, out, inputs, S_, D_, D_,
        (size_t)S_ * D_, (size_t)D_ * D_, (size_t)S_ * D_, (size_t)S_ * D_);
}

// Round 6
// 330.174 us; speedup vs baseline: 1.0996x; 1.0996x over previous
//
#include <hip/hip_runtime.h>
#include <hip/hip_bf16.h>
#include <hip/hip_fp16.h>

#define B_  4
#define S_  2048
#define D_  1024
#define E_  8
#define K2_ 2048   // 2*D

#define CHUNKS 64
#define CLEN   32  // CHUNKS*CLEN == S_

typedef __attribute__((ext_vector_type(8))) short short8;   // 8 bf16 (4 VGPRs)
typedef __attribute__((ext_vector_type(4))) float floatx4;  // 4 fp32 acc

__device__ __forceinline__ void gld16(const void* g, const void* l) {
    __builtin_amdgcn_global_load_lds(
        (const __attribute__((address_space(1))) unsigned int*)g,
        (__attribute__((address_space(3))) unsigned int*)l, 16, 0, 0);
}

// float -> bf16 bits (RNE)
__device__ __forceinline__ unsigned short f2bf(float f) {
    unsigned int u = __float_as_uint(f);
    u += 0x7fffu + ((u >> 16) & 1u);
    return (unsigned short)(u >> 16);
}

// ---------------- 1. RMSNorm (f32 in -> bf16 out), vectorized ----------------
__global__ void rmsnorm_k(const float* __restrict__ in, const float* __restrict__ nw,
                          __hip_bfloat16* __restrict__ x) {
    int b = blockIdx.y, s = blockIdx.x, t = threadIdx.x;
    const float4* row = (const float4*)(in + ((size_t)b * S_ + s) * D_);
    float4 v = row[t];
    float ss = v.x * v.x + v.y * v.y + v.z * v.z + v.w * v.w;
#pragma unroll
    for (int o = 32; o > 0; o >>= 1) ss += __shfl_down(ss, o, 64);
    __shared__ float ls[4];
    if ((t & 63) == 0) ls[t >> 6] = ss;
    __syncthreads();
    float tot = ls[0] + ls[1] + ls[2] + ls[3];
    float rs = rsqrtf(tot * (1.0f / (float)D_) + 1e-6f);
    float4 w = ((const float4*)nw)[t];
    ushort4 o;
    o.x = f2bf(v.x * rs * w.x); o.y = f2bf(v.y * rs * w.y);
    o.z = f2bf(v.z * rs * w.z); o.w = f2bf(v.w * rs * w.w);
    ((ushort4*)(x + ((size_t)b * S_ + s) * D_))[t] = o;
}

// ---------------- 2a. column sums of x over S (router mean) ----------------
__global__ void xsum_k(const __hip_bfloat16* __restrict__ x, float* __restrict__ xs) {
    int d = blockIdx.x * 256 + threadIdx.x;
    int b = blockIdx.y;
    int s0 = blockIdx.z * 128;
    const __hip_bfloat16* p = x + ((size_t)b * S_ + s0) * D_ + d;
    float acc = 0.0f;
#pragma unroll 4
    for (int s = 0; s < 128; s++) { acc += __bfloat162float(*p); p += D_; }
    atomicAdd(&xs[b * D_ + d], acc);
}

// ---------------- 2b. router logits + softmax (+ aux_loss=0) ----------------
__global__ void router_k(const float* __restrict__ xs, const float* __restrict__ rw,
                         const float* __restrict__ rb, float* __restrict__ probs,
                         float* __restrict__ aux) {
    int t = threadIdx.x;
    if (t == 255) *aux = 0.0f;
    int pair = t >> 3, sub = t & 7;
    int b = pair >> 3, e = pair & 7;
    float acc = 0.0f;
    for (int d = sub; d < D_; d += 8) acc += xs[b * D_ + d] * rw[e * D_ + d];
#pragma unroll
    for (int o = 4; o > 0; o >>= 1) acc += __shfl_down(acc, o, 8);
    __shared__ float lg[32];
    if (sub == 0) lg[pair] = acc * (1.0f / (float)S_) + rb[e];
    __syncthreads();
    if (t < 4) {
        float m = -1e30f;
        for (int e2 = 0; e2 < 8; e2++) m = fmaxf(m, lg[t * 8 + e2]);
        float ssum = 0.0f; float ex[8];
        for (int e2 = 0; e2 < 8; e2++) { ex[e2] = expf(lg[t * 8 + e2] - m); ssum += ex[e2]; }
        for (int e2 = 0; e2 < 8; e2++) probs[t * 8 + e2] = ex[e2] / ssum;
    }
}

// ---------------- 3. mix expert weights (float4 loads, bf16x4 stores) --------
__global__ void mix_k(const float* __restrict__ probs, const float* __restrict__ whg_e,
                      const float* __restrict__ wout_e, __hip_bfloat16* __restrict__ Whg,
                      __hip_bfloat16* __restrict__ Wout) {
    __shared__ float P[32];
    int t = threadIdx.x;
    if (t < 32) P[t] = probs[t];
    __syncthreads();
    size_t i4 = (size_t)blockIdx.x * 256 + t;          // float4 index
    const size_t T1q = (size_t)K2_ * D_ / 4;           // 524288
    const size_t T2q = (size_t)D_ * D_ / 4;            // 262144
    float4 a0 = {0,0,0,0}, a1 = {0,0,0,0}, a2 = {0,0,0,0}, a3 = {0,0,0,0};
    if (i4 < T1q) {
        const float4* src = (const float4*)whg_e;
#pragma unroll
        for (int e = 0; e < 8; e++) {
            float4 wv = src[(size_t)e * T1q + i4];
            float p0 = P[e], p1 = P[8 + e], p2 = P[16 + e], p3 = P[24 + e];
            a0.x += p0 * wv.x; a0.y += p0 * wv.y; a0.z += p0 * wv.z; a0.w += p0 * wv.w;
            a1.x += p1 * wv.x; a1.y += p1 * wv.y; a1.z += p1 * wv.z; a1.w += p1 * wv.w;
            a2.x += p2 * wv.x; a2.y += p2 * wv.y; a2.z += p2 * wv.z; a2.w += p2 * wv.w;
            a3.x += p3 * wv.x; a3.y += p3 * wv.y; a3.z += p3 * wv.z; a3.w += p3 * wv.w;
        }
        ushort4* dst = (ushort4*)Whg;
        ushort4 o;
        o.x = f2bf(a0.x); o.y = f2bf(a0.y); o.z = f2bf(a0.z); o.w = f2bf(a0.w);
        dst[0 * T1q + i4] = o;
        o.x = f2bf(a1.x); o.y = f2bf(a1.y); o.z = f2bf(a1.z); o.w = f2bf(a1.w);
        dst[1 * T1q + i4] = o;
        o.x = f2bf(a2.x); o.y = f2bf(a2.y); o.z = f2bf(a2.z); o.w = f2bf(a2.w);
        dst[2 * T1q + i4] = o;
        o.x = f2bf(a3.x); o.y = f2bf(a3.y); o.z = f2bf(a3.z); o.w = f2bf(a3.w);
        dst[3 * T1q + i4] = o;
    } else {
        size_t j4 = i4 - T1q;
        const float4* src = (const float4*)wout_e;
#pragma unroll
        for (int e = 0; e < 8; e++) {
            float4 wv = src[(size_t)e * T2q + j4];
            float p0 = P[e], p1 = P[8 + e], p2 = P[16 + e], p3 = P[24 + e];
            a0.x += p0 * wv.x; a0.y += p0 * wv.y; a0.z += p0 * wv.z; a0.w += p0 * wv.w;
            a1.x += p1 * wv.x; a1.y += p1 * wv.y; a1.z += p1 * wv.z; a1.w += p1 * wv.w;
            a2.x += p2 * wv.x; a2.y += p2 * wv.y; a2.z += p2 * wv.z; a2.w += p2 * wv.w;
            a3.x += p3 * wv.x; a3.y += p3 * wv.y; a3.z += p3 * wv.z; a3.w += p3 * wv.w;
        }
        ushort4* dst = (ushort4*)Wout;
        ushort4 o;
        o.x = f2bf(a0.x); o.y = f2bf(a0.y); o.z = f2bf(a0.z); o.w = f2bf(a0.w);
        dst[0 * T2q + j4] = o;
        o.x = f2bf(a1.x); o.y = f2bf(a1.y); o.z = f2bf(a1.z); o.w = f2bf(a1.w);
        dst[1 * T2q + j4] = o;
        o.x = f2bf(a2.x); o.y = f2bf(a2.y); o.z = f2bf(a2.z); o.w = f2bf(a2.w);
        dst[2 * T2q + j4] = o;
        o.x = f2bf(a3.x); o.y = f2bf(a3.y); o.z = f2bf(a3.z); o.w = f2bf(a3.w);
        dst[3 * T2q + j4] = o;
    }
}

// ---------------- 4. fused GEMM1 + (c,v) epilogue, 128m x 64n-dual tile ------
// (round-4 geometry: 32 KB LDS, VGPR~84, ~20% occupancy — best measured)
__global__ __launch_bounds__(256) void gemm_hg_cv(
    const __hip_bfloat16* __restrict__ A, const __hip_bfloat16* __restrict__ Bm,
    __half2* __restrict__ cv) {
    const int K = D_;
    int bz = blockIdx.z;
    A  += (size_t)bz * S_ * D_;
    Bm += (size_t)bz * K2_ * D_;
    __half2* CV = cv + (size_t)bz * S_ * D_;
    int m0 = blockIdx.y * 128, n0 = blockIdx.x * 64;
    __shared__ __hip_bfloat16 lA[128][64];
    __shared__ __hip_bfloat16 lBh[64][64];
    __shared__ __hip_bfloat16 lBg[64][64];
    int t = threadIdx.x;
    int w = t >> 6, lane = t & 63;
    int lm = lane & 15, quad = lane >> 4;
    int wr = w >> 1, wc = w & 1;             // wave tile: 64 m x 32 n (dual h/g)
    floatx4 acch[4][2] = {};
    floatx4 accg[4][2] = {};
    int srow = lane >> 3;                    // 0..7
    int swzb = ((lane & 7) ^ srow) * 16;     // swizzled source byte-chunk

    const __hip_bfloat16* Bh = Bm;                    // hidden rows 0..1023
    const __hip_bfloat16* Bg = Bm + (size_t)D_ * K;   // gate rows 1024..2047

    for (int k0 = 0; k0 < K; k0 += 64) {
#pragma unroll
        for (int it = 0; it < 4; it++) {
            int r0 = (w * 4 + it) * 8;
            gld16((const char*)(A + (size_t)(m0 + r0 + srow) * K + k0) + swzb,
                  &lA[r0][0]);
        }
#pragma unroll
        for (int it = 0; it < 2; it++) {
            int r0 = (w * 2 + it) * 8;
            gld16((const char*)(Bh + (size_t)(n0 + r0 + srow) * K + k0) + swzb,
                  &lBh[r0][0]);
            gld16((const char*)(Bg + (size_t)(n0 + r0 + srow) * K + k0) + swzb,
                  &lBg[r0][0]);
        }
        __syncthreads();
#pragma unroll
        for (int kk = 0; kk < 64; kk += 32) {
            short8 af[4], bh[2], bg[2];
            int p = (((kk >> 3) + quad) ^ (lm & 7)) * 8;
#pragma unroll
            for (int i = 0; i < 4; i++)
                af[i] = *(const short8*)(&lA[wr * 64 + i * 16 + lm][p]);
#pragma unroll
            for (int j = 0; j < 2; j++) {
                bh[j] = *(const short8*)(&lBh[wc * 32 + j * 16 + lm][p]);
                bg[j] = *(const short8*)(&lBg[wc * 32 + j * 16 + lm][p]);
            }
#pragma unroll
            for (int i = 0; i < 4; i++)
#pragma unroll
                for (int j = 0; j < 2; j++) {
                    acch[i][j] = __builtin_amdgcn_mfma_f32_16x16x32_bf16(
                        af[i], bh[j], acch[i][j], 0, 0, 0);
                    accg[i][j] = __builtin_amdgcn_mfma_f32_16x16x32_bf16(
                        af[i], bg[j], accg[i][j], 0, 0, 0);
                }
        }
        __syncthreads();
    }
#pragma unroll
    for (int i = 0; i < 4; i++) {
#pragma unroll
        for (int j = 0; j < 2; j++) {
#pragma unroll
            for (int r = 0; r < 4; r++) {
                int m = m0 + wr * 64 + i * 16 + quad * 4 + r;
                int n = n0 + wc * 32 + j * 16 + lm;
                float hid = acch[i][j][r];
                float g   = accg[i][j][r];
                float c  = 1.0f / (1.0f + expf(g));    // sigmoid(-g)
                float sg = 1.0f / (1.0f + expf(-g));   // sigmoid(g)
                float gfn = (hid >= 0.0f) ? (hid + 0.5f)
                                          : (1.0f / (1.0f + expf(-hid)));
                CV[(size_t)m * D_ + n] = __floats2half2_rn(c, sg * gfn);
            }
        }
    }
}

// ---------------- 6. bf16 MFMA GEMM, C = A * B^T (+R), XOR-swizzled LDS ----
#define TM 128
#define TN 128
#define TBK 64
__global__ __launch_bounds__(256) void gemm_bf16_bt(
    const __hip_bfloat16* __restrict__ A, const __hip_bfloat16* __restrict__ Bm,
    float* __restrict__ C, const float* __restrict__ R,
    int M, int N, int K, size_t sa, size_t sb, size_t sc, size_t sr) {
    int bz = blockIdx.z;
    A += (size_t)bz * sa; Bm += (size_t)bz * sb; C += (size_t)bz * sc;
    if (R) R += (size_t)bz * sr;
    int m0 = blockIdx.y * TM, n0 = blockIdx.x * TN;
    __shared__ __hip_bfloat16 lA[TM][TBK];
    __shared__ __hip_bfloat16 lB[TN][TBK];
    int t = threadIdx.x;
    int w = t >> 6, lane = t & 63;
    int lm = lane & 15, quad = lane >> 4;
    int wr = w >> 1, wc = w & 1;
    floatx4 acc[4][4] = {};
    int srow = lane >> 3;
    int swzb = ((lane & 7) ^ srow) * 16;

    for (int k0 = 0; k0 < K; k0 += TBK) {
#pragma unroll
        for (int it = 0; it < 4; it++) {
            int r0 = (w * 4 + it) * 8;
            gld16((const char*)(A + (size_t)(m0 + r0 + srow) * K + k0) + swzb,
                  &lA[r0][0]);
            gld16((const char*)(Bm + (size_t)(n0 + r0 + srow) * K + k0) + swzb,
                  &lB[r0][0]);
        }
        __syncthreads();
#pragma unroll
        for (int kk = 0; kk < TBK; kk += 32) {
            short8 af[4], bf[4];
            int p = (((kk >> 3) + quad) ^ (lm & 7)) * 8;
#pragma unroll
            for (int i = 0; i < 4; i++)
                af[i] = *(const short8*)(&lA[wr * 64 + i * 16 + lm][p]);
#pragma unroll
            for (int j = 0; j < 4; j++)
                bf[j] = *(const short8*)(&lB[wc * 64 + j * 16 + lm][p]);
#pragma unroll
            for (int i = 0; i < 4; i++)
#pragma unroll
                for (int j = 0; j < 4; j++)
                    acc[i][j] = __builtin_amdgcn_mfma_f32_16x16x32_bf16(
                        af[i], bf[j], acc[i][j], 0, 0, 0);
        }
        __syncthreads();
    }
#pragma unroll
    for (int i = 0; i < 4; i++) {
#pragma unroll
        for (int j = 0; j < 4; j++) {
#pragma unroll
            for (int r = 0; r < 4; r++) {
                int m = m0 + wr * 64 + i * 16 + quad * 4 + r;
                int n = n0 + wc * 64 + j * 16 + lm;
                float v = acc[i][j][r];
                if (R) v += R[(size_t)m * N + n];
                C[(size_t)m * N + n] = v;
            }
        }
    }
}

// ---------------- 5. chunked LINEAR scan over half2 cv (4 d's per thread) ----
// phase A: per-chunk composition. grid (CHUNKS, B_), block 256.
__global__ void scanA_k(const __half2* __restrict__ cv, float* __restrict__ Cc,
                        float* __restrict__ Vc) {
    int c = blockIdx.x, b = blockIdx.y, t = threadIdx.x;
    const float4* p = (const float4*)(cv + (size_t)(b * S_ + c * CLEN) * D_) + t;
    float P0 = 1, P1 = 1, P2 = 1, P3 = 1;
    float V0 = 0, V1 = 0, V2 = 0, V3 = 0;
#pragma unroll 4
    for (int s = 0; s < CLEN; s++) {
        float4 raw = p[(size_t)s * (D_ / 4)];
        const __half2* e = (const __half2*)&raw;
        float c0 = __low2float(e[0]), v0 = __high2float(e[0]);
        float c1 = __low2float(e[1]), v1 = __high2float(e[1]);
        float c2 = __low2float(e[2]), v2 = __high2float(e[2]);
        float c3 = __low2float(e[3]), v3 = __high2float(e[3]);
        P0 *= c0; V0 = fmaf(c0, V0, v0);
        P1 *= c1; V1 = fmaf(c1, V1, v1);
        P2 *= c2; V2 = fmaf(c2, V2, v2);
        P3 *= c3; V3 = fmaf(c3, V3, v3);
    }
    size_t q = ((size_t)(b * CHUNKS + c)) * (D_ / 4) + t;
    ((float4*)Cc)[q] = make_float4(P0, P1, P2, P3);
    ((float4*)Vc)[q] = make_float4(V0, V1, V2, V3);
}

// phase C with inline lookback over Cc/Vc (L2-hot). grid (CHUNKS, B_), 256.
__global__ void scanC_k(const __half2* __restrict__ cv, const float* __restrict__ Cc,
                        const float* __restrict__ Vc,
                        __hip_bfloat16* __restrict__ hout, float* __restrict__ ns) {
    int c = blockIdx.x, b = blockIdx.y, t = threadIdx.x;
    float h0 = 0, h1 = 0, h2 = 0, h3 = 0;
#pragma unroll 4
    for (int cc = 0; cc < c; cc++) {
        size_t q = ((size_t)(b * CHUNKS + cc)) * (D_ / 4) + t;
        float4 C4 = ((const float4*)Cc)[q];
        float4 V4 = ((const float4*)Vc)[q];
        h0 = fmaf(C4.x, h0, V4.x); h1 = fmaf(C4.y, h1, V4.y);
        h2 = fmaf(C4.z, h2, V4.z); h3 = fmaf(C4.w, h3, V4.w);
    }
    const float4* p = (const float4*)(cv + (size_t)(b * S_ + c * CLEN) * D_) + t;
    ushort4* hq = (ushort4*)(hout + (size_t)(b * S_ + c * CLEN) * D_) + t;
#pragma unroll 4
    for (int s = 0; s < CLEN; s++) {
        float4 raw = p[(size_t)s * (D_ / 4)];
        const __half2* e = (const __half2*)&raw;
        h0 = fmaf(__low2float(e[0]), h0, __high2float(e[0]));
        h1 = fmaf(__low2float(e[1]), h1, __high2float(e[1]));
        h2 = fmaf(__low2float(e[2]), h2, __high2float(e[2]));
        h3 = fmaf(__low2float(e[3]), h3, __high2float(e[3]));
        ushort4 o;
        o.x = f2bf(h0); o.y = f2bf(h1); o.z = f2bf(h2); o.w = f2bf(h3);
        hq[(size_t)s * (D_ / 4)] = o;
    }
    if (c == CHUNKS - 1)
        ((float4*)(ns + (size_t)b * D_))[t] = make_float4(h0, h1, h2, h3);
}

// ---------------- launcher ----------------
extern "C" void kernel_launch(void* const* d_in, const int* in_sizes, int n_in,
                              void* d_out_v, int out_size, void* d_ws, size_t ws_size,
                              hipStream_t stream) {
    const float* inputs = (const float*)d_in[0];
    const float* nw     = (const float*)d_in[1];
    const float* rw     = (const float*)d_in[2];
    const float* rb     = (const float*)d_in[3];
    const float* whg_e  = (const float*)d_in[4];
    const float* wout_e = (const float*)d_in[5];
    float* out = (float*)d_out_v;

    float* ws = (float*)d_ws;
    __half2*        cv      = (__half2*)ws;                     // 8388608 half2 (33.5 MB)
    __hip_bfloat16* x_bf    = (__hip_bfloat16*)(ws + 8388608);  // 8388608 bf16
    __hip_bfloat16* h_bf    = (__hip_bfloat16*)(ws + 12582912); // 8388608 bf16
    __hip_bfloat16* Whg_bf  = (__hip_bfloat16*)(ws + 16777216); // 8388608 bf16
    __hip_bfloat16* Wout_bf = (__hip_bfloat16*)(ws + 20971520); // 4194304 bf16
    float* xsum  = ws + 23068672;  // 4096
    float* probs = ws + 23072768;  // 32
    float* Cc    = ws + 23072800;  // 262144
    float* Vc    = ws + 23334944;  // 262144

    hipMemsetAsync(xsum, 0, (size_t)B_ * D_ * sizeof(float), stream);

    rmsnorm_k<<<dim3(S_, B_), 256, 0, stream>>>(inputs, nw, x_bf);
    xsum_k<<<dim3(D_ / 256, B_, 16), 256, 0, stream>>>(x_bf, xsum);
    router_k<<<1, 256, 0, stream>>>(xsum, rw, rb, probs,
                                    out + (size_t)B_ * S_ * D_ + (size_t)B_ * D_);
    mix_k<<<3072, 256, 0, stream>>>(probs, whg_e, wout_e, Whg_bf, Wout_bf);

    // fused GEMM1 + (c,v): 128m x 64n-dual tile
    gemm_hg_cv<<<dim3(D_ / 64, S_ / 128, B_), 256, 0, stream>>>(x_bf, Whg_bf, cv);

    scanA_k<<<dim3(CHUNKS, B_), 256, 0, stream>>>(cv, Cc, Vc);
    scanC_k<<<dim3(CHUNKS, B_), 256, 0, stream>>>(
        cv, Cc, Vc, h_bf, out + (size_t)B_ * S_ * D_);

    // out[b] = h[b] (2048x1024) * Wout[b]^T + inputs[b]
    gemm_bf16_bt<<<dim3(D_ / TN, S_ / TM, B_), 256, 0, stream>>>(
        h_bf, Wout_bf, out, inputs, S_, D_, D_,
        (size_t)S_ * D_, (size_t)D_ * D_, (size_t)S_ * D_, (size_t)S_ * D_);
}